// Round 6
// baseline (203.157 us; speedup 1.0000x reference)
//
#include <hip/hip_runtime.h>
#include <hip/hip_bf16.h>
#include <math.h>

// MIL_Cluster_FC round 6:
//  - REVERT gemm1 to global_load_lds staging (R5 reg-staged fp32 path was
//    latency-bound: 90us, MfmaUtil 9%). New: A-rows gathered IN gemm1 via
//    per-lane global source addresses (m173-verified), LDS linear dest.
//  - k_convertlin: pure linear fp32->bf16 cast (no gather, no bucket dep)
//  - single-kernel bucketing (ballot-aggregated hist + scatter, pad-fill)
//  - merged W1+W2 transpose kernel
//  - dispatches 14 -> 10

#define C_NUM 10
#define D_IN 1024
#define D_H 512
#define D_ATT 256
#define N_CLS 4
#define BM 128
#define BN 128
#define BKS 64

typedef __attribute__((ext_vector_type(8))) short short8v;
typedef __attribute__((ext_vector_type(4))) short short4v;
typedef __attribute__((ext_vector_type(4))) float f32x4;

__device__ __forceinline__ short f2bf(float f) {
    __hip_bfloat16 h = __float2bfloat16(f);
    return *reinterpret_cast<short*>(&h);
}

__device__ __forceinline__ void gload_lds16(const void* g, void* l) {
    __builtin_amdgcn_global_load_lds((const __attribute__((address_space(1))) unsigned int*)g,
                                     (__attribute__((address_space(3))) unsigned int*)l,
                                     16, 0, 0);
}

// bijective XCD-chunked swizzle (m204): consecutive swizzled ids -> same XCD
__device__ __forceinline__ int xcd_swizzle(int orig, int nwg) {
    int q = nwg >> 3, r = nwg & 7;
    int xcd = orig & 7, base = orig >> 3;
    return (xcd < r ? xcd * (q + 1) : r * (q + 1) + (xcd - r) * q) + base;
}

// ---- single-kernel bucketing: hist (ballot-agg) -> offsets -> pad-fill ->
// scatter (ballot-ranked). One block, 1024 threads. ----
__global__ __launch_bounds__(1024) void k_bucket(const int* __restrict__ cid, int n,
                                                 int* counts, int* aoff, int* bucket) {
    __shared__ int lc[C_NUM];
    __shared__ int lcur[C_NUM];
    __shared__ int loff[C_NUM + 1];
    int tid = threadIdx.x, lane = tid & 63;
    if (tid < C_NUM) lc[tid] = 0;
    __syncthreads();
    for (int i0 = 0; i0 < n; i0 += 1024) {
        int i = i0 + tid;
        int c = (i < n) ? cid[i] : -1;
#pragma unroll
        for (int cc = 0; cc < C_NUM; ++cc) {
            unsigned long long m = __ballot(c == cc);
            if (m != 0ull && lane == __ffsll(m) - 1)
                atomicAdd(&lc[cc], __popcll(m));
        }
    }
    __syncthreads();
    if (tid == 0) {
        int off = 0;
        for (int c = 0; c < C_NUM; ++c) {
            loff[c] = off; lcur[c] = off;
            off += ((lc[c] + BM - 1) / BM) * BM;
        }
        loff[C_NUM] = off;
    }
    __syncthreads();
    if (tid < C_NUM) { counts[tid] = lc[tid]; aoff[tid] = loff[tid]; }
    if (tid == C_NUM) aoff[C_NUM] = loff[C_NUM];
    // pad slots -> -1
    for (int c = 0; c < C_NUM; ++c)
        for (int i = loff[c] + lc[c] + tid; i < loff[c + 1]; i += 1024) bucket[i] = -1;
    // scatter with wave-aggregated ranks (order within cluster irrelevant)
    for (int i0 = 0; i0 < n; i0 += 1024) {
        int i = i0 + tid;
        int c = (i < n) ? cid[i] : -1;
#pragma unroll
        for (int cc = 0; cc < C_NUM; ++cc) {
            unsigned long long m = __ballot(c == cc);
            if (c == cc) {
                int leader = __ffsll(m) - 1;
                int rank = __popcll(m & ((1ull << lane) - 1ull));
                int base = 0;
                if (lane == leader) base = atomicAdd(&lcur[cc], __popcll(m));
                base = __shfl(base, leader, 64);
                bucket[base + rank] = i;
            }
        }
    }
}

// linear fp32 -> bf16 cast of x (coalesced, no gather)
__global__ __launch_bounds__(256) void k_convertlin(const float* __restrict__ x,
                                                    short* __restrict__ xbl) {
    size_t i = (size_t)blockIdx.x * 256 + threadIdx.x;
    const f32x4* p = (const f32x4*)(x + i * 8);
    f32x4 f0 = p[0], f1 = p[1];
    short8v v;
#pragma unroll
    for (int e = 0; e < 4; ++e) { v[e] = f2bf(f0[e]); v[4 + e] = f2bf(f1[e]); }
    *(short8v*)&xbl[i * 8] = v;
}

// merged W1+W2 transpose: [C][K][N] fp32 -> [C][N][K] bf16
__global__ __launch_bounds__(256) void k_transpose2(
    const float* __restrict__ W1, short* __restrict__ Wt1,
    const float* __restrict__ W2, short* __restrict__ Wt2)
{
    __shared__ float t[64][65];
    int bid = blockIdx.x;
    const float* src; short* dst; int K, N, k0, n0;
    if (bid < C_NUM * 128) {            // W1: K=1024 (16 blk) x N=512 (8 blk)
        int cc = bid >> 7, r = bid & 127;
        k0 = (r & 15) * 64; n0 = (r >> 4) * 64;
        src = W1 + (size_t)cc * D_IN * D_H; dst = Wt1 + (size_t)cc * D_H * D_IN;
        K = D_IN; N = D_H;
    } else {                            // W2: K=512 (8 blk) x N=512 (8 blk)
        int idx = bid - C_NUM * 128;
        int cc = idx >> 6, r = idx & 63;
        k0 = (r & 7) * 64; n0 = (r >> 3) * 64;
        src = W2 + (size_t)cc * D_H * D_H; dst = Wt2 + (size_t)cc * D_H * D_H;
        K = D_H; N = D_H;
    }
    int tid = threadIdx.x;
    int tk = tid >> 4, tn4 = (tid & 15) * 4;
#pragma unroll
    for (int it = 0; it < 4; ++it) {
        int k = tk + it * 16;
        f32x4 v = *(const f32x4*)&src[(size_t)(k0 + k) * N + n0 + tn4];
        t[k][tn4 + 0] = v[0]; t[k][tn4 + 1] = v[1];
        t[k][tn4 + 2] = v[2]; t[k][tn4 + 3] = v[3];
    }
    __syncthreads();
    int wn = tid >> 2, kq = (tid & 3) * 16;
#pragma unroll
    for (int q = 0; q < 4; ++q) {
        int k = kq + q * 4;
        short4v o;
#pragma unroll
        for (int e = 0; e < 4; ++e) o[e] = f2bf(t[k + e][wn]);
        *(short4v*)&dst[(size_t)(n0 + wn) * K + k0 + k] = o;
    }
}

// gemm1 (gathered): h1 = relu(xbl[bucket] @ W1t^T + b1); A gathered via
// per-lane global_load_lds source addresses, linear LDS dest, XOR slot swizzle.
__global__ __launch_bounds__(256) void k_gemm1g(
    const short* __restrict__ xbl, const short* __restrict__ Wt, const float* __restrict__ b1,
    const int* __restrict__ bucket, const int* __restrict__ aoff, short* __restrict__ h1)
{
    __shared__ short As[BM * BKS];
    __shared__ short Bs[BN * BKS];
    __shared__ int ridx[BM];

    int wg = xcd_swizzle(blockIdx.x, gridDim.x);
    int rowStart = (wg >> 2) * BM;
    if (rowStart >= aoff[C_NUM]) return;
    int c = 0;
    while (c < C_NUM - 1 && rowStart >= aoff[c + 1]) ++c;
    int colStart = (wg & 3) * BN;

    int tid = threadIdx.x;
    int lane = tid & 63;
    int wid = tid >> 6;
    int wm = wid >> 1, wn = wid & 1;

    if (tid < BM) ridx[tid] = bucket[rowStart + tid];
    __syncthreads();

    int l8 = lane >> 3;
    int sslot = (lane & 7) ^ l8;
    // per-lane gathered A-row base for each staging quarter
    const short* aq[4];
#pragma unroll
    for (int q = 0; q < 4; ++q) {
        int rr = ridx[(q * 4 + wid) * 8 + l8];
        aq[q] = xbl + (size_t)(rr < 0 ? 0 : rr) * D_IN + sslot * 8;
    }
    const short* bbase = Wt + ((size_t)c * D_H + colStart + l8) * D_IN + sslot * 8;

    f32x4 acc[4][4];
#pragma unroll
    for (int i = 0; i < 4; ++i)
#pragma unroll
        for (int j = 0; j < 4; ++j)
            acc[i][j] = f32x4{0.f, 0.f, 0.f, 0.f};

    for (int k0 = 0; k0 < D_IN; k0 += BKS) {
#pragma unroll
        for (int q = 0; q < 4; ++q) {
            int rb = (q * 4 + wid) * 8;
            gload_lds16(aq[q] + k0, &As[rb * BKS]);
            gload_lds16(bbase + (size_t)rb * D_IN + k0, &Bs[rb * BKS]);
        }
        __syncthreads();
#pragma unroll
        for (int kk = 0; kk < 2; ++kk) {
            short8v af[4], bfr[4];
#pragma unroll
            for (int i = 0; i < 4; ++i) {
                int row = wm * 64 + i * 16 + (lane & 15);
                int slot = (kk * 4 + (lane >> 4)) ^ (row & 7);
                af[i] = *(const short8v*)&As[row * BKS + slot * 8];
            }
#pragma unroll
            for (int j = 0; j < 4; ++j) {
                int nn = wn * 64 + j * 16 + (lane & 15);
                int slot = (kk * 4 + (lane >> 4)) ^ (nn & 7);
                bfr[j] = *(const short8v*)&Bs[nn * BKS + slot * 8];
            }
#pragma unroll
            for (int i = 0; i < 4; ++i)
#pragma unroll
                for (int j = 0; j < 4; ++j)
                    acc[i][j] = __builtin_amdgcn_mfma_f32_16x16x32_bf16(af[i], bfr[j], acc[i][j], 0, 0, 0);
        }
        __syncthreads();
    }

    const float* bias = b1 + c * D_H;
    float bj[4];
#pragma unroll
    for (int j = 0; j < 4; ++j) bj[j] = bias[colStart + wn * 64 + j * 16 + (lane & 15)];
#pragma unroll
    for (int i = 0; i < 4; ++i) {
#pragma unroll
        for (int r = 0; r < 4; ++r) {
            int rowl = wm * 64 + i * 16 + (lane >> 4) * 4 + r;
            bool valid = (ridx[rowl] >= 0);
            size_t gro = (size_t)(rowStart + rowl) * D_H + colStart + wn * 64 + (lane & 15);
#pragma unroll
            for (int j = 0; j < 4; ++j) {
                float v = valid ? fmaxf(acc[i][j][r] + bj[j], 0.f) : 0.f;
                h1[gro + j * 16] = f2bf(v);
            }
        }
    }
}

// gemm1 fallback (small ws): reg-staged fp32 x -> bf16 (correctness-safe)
__global__ __launch_bounds__(256) void k_gemm1f(
    const float* __restrict__ x, const short* __restrict__ Wt, const float* __restrict__ b1,
    const int* __restrict__ bucket, const int* __restrict__ aoff, short* __restrict__ h1)
{
    __shared__ short As[BM * BKS];
    __shared__ short Bs[BN * BKS];
    __shared__ int ridx[BM];

    int rowStart = blockIdx.x * BM;
    if (rowStart >= aoff[C_NUM]) return;
    int c = 0;
    while (c < C_NUM - 1 && rowStart >= aoff[c + 1]) ++c;
    int colStart = blockIdx.y * BN;

    int tid = threadIdx.x;
    int lane = tid & 63;
    int wid = tid >> 6;
    int wm = wid >> 1, wn = wid & 1;

    if (tid < BM) ridx[tid] = bucket[rowStart + tid];
    __syncthreads();

    int arow = tid >> 1;
    int khalf = tid & 1;
    int agr = ridx[arow];
    const float* aptr = x + (size_t)(agr < 0 ? 0 : agr) * D_IN + khalf * 32;

    int l8 = lane >> 3;
    int sslot = (lane & 7) ^ l8;
    const short* bbase = Wt + ((size_t)c * D_H + colStart + l8) * D_IN + sslot * 8;

    f32x4 acc[4][4];
#pragma unroll
    for (int i = 0; i < 4; ++i)
#pragma unroll
        for (int j = 0; j < 4; ++j)
            acc[i][j] = f32x4{0.f, 0.f, 0.f, 0.f};

    for (int k0 = 0; k0 < D_IN; k0 += BKS) {
#pragma unroll
        for (int q = 0; q < 4; ++q) {
            int nbase = (q * 4 + wid) * 8;
            gload_lds16(bbase + (size_t)nbase * D_IN + k0, &Bs[nbase * BKS]);
        }
        {
            const f32x4* p = (const f32x4*)(aptr + k0);
#pragma unroll
            for (int q = 0; q < 4; ++q) {
                f32x4 f0 = {0.f, 0.f, 0.f, 0.f}, f1 = {0.f, 0.f, 0.f, 0.f};
                if (agr >= 0) { f0 = p[2 * q]; f1 = p[2 * q + 1]; }
                short8v v;
#pragma unroll
                for (int e = 0; e < 4; ++e) { v[e] = f2bf(f0[e]); v[4 + e] = f2bf(f1[e]); }
                int slot = (khalf * 4 + q) ^ (arow & 7);
                *(short8v*)&As[arow * BKS + slot * 8] = v;
            }
        }
        __syncthreads();
#pragma unroll
        for (int kk = 0; kk < 2; ++kk) {
            short8v af[4], bfr[4];
#pragma unroll
            for (int i = 0; i < 4; ++i) {
                int row = wm * 64 + i * 16 + (lane & 15);
                int slot = (kk * 4 + (lane >> 4)) ^ (row & 7);
                af[i] = *(const short8v*)&As[row * BKS + slot * 8];
            }
#pragma unroll
            for (int j = 0; j < 4; ++j) {
                int nn = wn * 64 + j * 16 + (lane & 15);
                int slot = (kk * 4 + (lane >> 4)) ^ (nn & 7);
                bfr[j] = *(const short8v*)&Bs[nn * BKS + slot * 8];
            }
#pragma unroll
            for (int i = 0; i < 4; ++i)
#pragma unroll
                for (int j = 0; j < 4; ++j)
                    acc[i][j] = __builtin_amdgcn_mfma_f32_16x16x32_bf16(af[i], bfr[j], acc[i][j], 0, 0, 0);
        }
        __syncthreads();
    }

    const float* bias = b1 + c * D_H;
    float bj[4];
#pragma unroll
    for (int j = 0; j < 4; ++j) bj[j] = bias[colStart + wn * 64 + j * 16 + (lane & 15)];
#pragma unroll
    for (int i = 0; i < 4; ++i) {
#pragma unroll
        for (int r = 0; r < 4; ++r) {
            int rowl = wm * 64 + i * 16 + (lane >> 4) * 4 + r;
            bool valid = (ridx[rowl] >= 0);
            size_t gro = (size_t)(rowStart + rowl) * D_H + colStart + wn * 64 + (lane & 15);
#pragma unroll
            for (int j = 0; j < 4; ++j) {
                float v = valid ? fmaxf(acc[i][j][r] + bj[j], 0.f) : 0.f;
                h1[gro + j * 16] = f2bf(v);
            }
        }
    }
}

// pooled[c,:] += column-sum over real rows of relu(h1 @ W2[c] + b2[c])
__global__ __launch_bounds__(256) void k_gemm2_mfma(
    const short* __restrict__ h1, const short* __restrict__ Wt, const float* __restrict__ b2,
    const int* __restrict__ bucket, const int* __restrict__ aoff, float* __restrict__ pooled)
{
    __shared__ short As[BM * BKS];
    __shared__ short Bs[BN * BKS];
    __shared__ int ridx[BM];

    int wg = xcd_swizzle(blockIdx.x, gridDim.x);
    int rowStart = (wg >> 2) * BM;
    if (rowStart >= aoff[C_NUM]) return;
    int c = 0;
    while (c < C_NUM - 1 && rowStart >= aoff[c + 1]) ++c;
    int colStart = (wg & 3) * BN;

    int tid = threadIdx.x;
    int lane = tid & 63;
    int wid = tid >> 6;
    int wm = wid >> 1, wn = wid & 1;

    if (tid < BM) ridx[tid] = bucket[rowStart + tid];

    int l8 = lane >> 3;
    int sslot = (lane & 7) ^ l8;
    const short* abase = h1 + (size_t)(rowStart + l8) * D_H + sslot * 8;
    const short* bbase = Wt + ((size_t)c * D_H + colStart + l8) * D_H + sslot * 8;

    f32x4 acc[4][4];
#pragma unroll
    for (int i = 0; i < 4; ++i)
#pragma unroll
        for (int j = 0; j < 4; ++j)
            acc[i][j] = f32x4{0.f, 0.f, 0.f, 0.f};

    for (int k0 = 0; k0 < D_H; k0 += BKS) {
#pragma unroll
        for (int q = 0; q < 4; ++q) {
            int rb = (q * 4 + wid) * 8;
            gload_lds16(abase + (size_t)rb * D_H + k0, &As[rb * BKS]);
            gload_lds16(bbase + (size_t)rb * D_H + k0, &Bs[rb * BKS]);
        }
        __syncthreads();
#pragma unroll
        for (int kk = 0; kk < 2; ++kk) {
            short8v af[4], bfr[4];
#pragma unroll
            for (int i = 0; i < 4; ++i) {
                int row = wm * 64 + i * 16 + (lane & 15);
                int slot = (kk * 4 + (lane >> 4)) ^ (row & 7);
                af[i] = *(const short8v*)&As[row * BKS + slot * 8];
            }
#pragma unroll
            for (int j = 0; j < 4; ++j) {
                int nn = wn * 64 + j * 16 + (lane & 15);
                int slot = (kk * 4 + (lane >> 4)) ^ (nn & 7);
                bfr[j] = *(const short8v*)&Bs[nn * BKS + slot * 8];
            }
#pragma unroll
            for (int i = 0; i < 4; ++i)
#pragma unroll
                for (int j = 0; j < 4; ++j)
                    acc[i][j] = __builtin_amdgcn_mfma_f32_16x16x32_bf16(af[i], bfr[j], acc[i][j], 0, 0, 0);
        }
        __syncthreads();
    }

    const float* bias = b2 + c * D_H;
    float bj[4];
#pragma unroll
    for (int j = 0; j < 4; ++j) bj[j] = bias[colStart + wn * 64 + j * 16 + (lane & 15)];
    float csum[4] = {0.f, 0.f, 0.f, 0.f};
#pragma unroll
    for (int i = 0; i < 4; ++i) {
#pragma unroll
        for (int r = 0; r < 4; ++r) {
            int rowl = wm * 64 + i * 16 + (lane >> 4) * 4 + r;
            float m = (ridx[rowl] >= 0) ? 1.f : 0.f;
#pragma unroll
            for (int j = 0; j < 4; ++j)
                csum[j] += m * fmaxf(acc[i][j][r] + bj[j], 0.f);
        }
    }
#pragma unroll
    for (int j = 0; j < 4; ++j) {
        float s = csum[j];
        s += __shfl_xor(s, 16, 64);
        s += __shfl_xor(s, 32, 64);
        if ((lane >> 4) == 0)
            atomicAdd(&pooled[c * D_H + colStart + wn * 64 + j * 16 + lane], s);
    }
}

// ---- tail stage A ----
__global__ __launch_bounds__(256) void k_tA(
    const float* __restrict__ pooled, const int* __restrict__ counts,
    const float* __restrict__ Wfc, const float* __restrict__ bfc,
    float* __restrict__ hfc)
{
    __shared__ float hcs[C_NUM][D_H];
    __shared__ float red[4][64][C_NUM];
    int tid = threadIdx.x;
    for (int idx = tid; idx < C_NUM * D_H; idx += 256) {
        int cc = idx >> 9;
        hcs[cc][idx & (D_H - 1)] = pooled[idx] / fmaxf((float)counts[cc], 1.f);
    }
    __syncthreads();
    int col = blockIdx.x * 64 + (tid & 63);
    int kq = tid >> 6, k0 = kq * 128;
    float acc[C_NUM] = {};
    for (int k = 0; k < 128; ++k) {
        float wv = Wfc[(size_t)(k0 + k) * D_H + col];
#pragma unroll
        for (int cc = 0; cc < C_NUM; ++cc) acc[cc] += hcs[cc][k0 + k] * wv;
    }
#pragma unroll
    for (int cc = 0; cc < C_NUM; ++cc) red[kq][tid & 63][cc] = acc[cc];
    __syncthreads();
    if (kq == 0) {
        float bv = bfc[col];
#pragma unroll
        for (int cc = 0; cc < C_NUM; ++cc) {
            float s = red[0][tid][cc] + red[1][tid][cc] + red[2][tid][cc] + red[3][tid][cc];
            hfc[cc * D_H + col] = fmaxf(s + bv, 0.f);
        }
    }
}

// ---- tail stage B ----
__global__ __launch_bounds__(256) void k_tB(
    const float* __restrict__ hfc,
    const float* __restrict__ Wa, const float* __restrict__ ba,
    const float* __restrict__ Wb, const float* __restrict__ bb,
    const float* __restrict__ Wc,
    float* __restrict__ scores)
{
    __shared__ float hfs[C_NUM][D_H];
    __shared__ float red[4][64][C_NUM][2];
    int tid = threadIdx.x;
    for (int idx = tid; idx < C_NUM * D_H; idx += 256) {
        hfs[idx >> 9][idx & (D_H - 1)] = hfc[idx];
    }
    __syncthreads();
    int ad = blockIdx.x * 64 + (tid & 63);
    int kq = tid >> 6, k0 = kq * 128;
    float sa[C_NUM] = {}, sb[C_NUM] = {};
    for (int k = 0; k < 128; ++k) {
        float wav = Wa[(size_t)(k0 + k) * D_ATT + ad];
        float wbv = Wb[(size_t)(k0 + k) * D_ATT + ad];
#pragma unroll
        for (int cc = 0; cc < C_NUM; ++cc) {
            float h = hfs[cc][k0 + k];
            sa[cc] += h * wav;
            sb[cc] += h * wbv;
        }
    }
#pragma unroll
    for (int cc = 0; cc < C_NUM; ++cc) {
        red[kq][tid & 63][cc][0] = sa[cc];
        red[kq][tid & 63][cc][1] = sb[cc];
    }
    __syncthreads();
    if (kq == 0) {
        float bav = ba[ad], bbv = bb[ad], wcv = Wc[ad];
#pragma unroll
        for (int cc = 0; cc < C_NUM; ++cc) {
            float sat = red[0][tid][cc][0] + red[1][tid][cc][0] + red[2][tid][cc][0] + red[3][tid][cc][0];
            float sbt = red[0][tid][cc][1] + red[1][tid][cc][1] + red[2][tid][cc][1] + red[3][tid][cc][1];
            float v = tanhf(sat + bav) * (1.f / (1.f + expf(-(sbt + bbv)))) * wcv;
            v += __shfl_xor(v, 1, 64); v += __shfl_xor(v, 2, 64); v += __shfl_xor(v, 4, 64);
            v += __shfl_xor(v, 8, 64); v += __shfl_xor(v, 16, 64); v += __shfl_xor(v, 32, 64);
            if (tid == 0) atomicAdd(&scores[cc], v);
        }
    }
}

// ---- tail stage C+D fused ----
__global__ __launch_bounds__(256) void k_tCD(
    const float* __restrict__ scores, const float* __restrict__ bc,
    const float* __restrict__ hfc, const float* __restrict__ Wrho,
    float* __restrict__ hr_raw)
{
    __shared__ float hps[32];
    int tid = threadIdx.x;
    int k0 = blockIdx.x * 32;
    if (tid < 32) {
        float sc2[C_NUM];
        float mx = -1e30f;
#pragma unroll
        for (int cc = 0; cc < C_NUM; ++cc) { sc2[cc] = scores[cc] + bc[0]; mx = fmaxf(mx, sc2[cc]); }
        float sum = 0.f;
#pragma unroll
        for (int cc = 0; cc < C_NUM; ++cc) { sc2[cc] = expf(sc2[cc] - mx); sum += sc2[cc]; }
        float s = 0.f;
#pragma unroll
        for (int cc = 0; cc < C_NUM; ++cc) s += (sc2[cc] / sum) * hfc[cc * D_H + k0 + tid];
        hps[tid] = s;
    }
    __syncthreads();
    float acc = 0.f;
#pragma unroll 8
    for (int k = 0; k < 32; ++k)
        acc += hps[k] * Wrho[(size_t)(k0 + k) * D_ATT + tid];
    atomicAdd(&hr_raw[tid], acc);
}

// ---- tail stage E ----
__global__ __launch_bounds__(256) void k_tE(
    const float* __restrict__ hr_raw, const float* __restrict__ brho,
    const float* __restrict__ Wcls, const float* __restrict__ bcls,
    float* __restrict__ out)
{
    __shared__ float cpart[4][N_CLS];
    int tid = threadIdx.x, lane = tid & 63, w = tid >> 6;
    float h = fmaxf(hr_raw[tid] + brho[tid], 0.f);
    f32x4 wv = *(const f32x4*)&Wcls[tid * N_CLS];
    float v[N_CLS];
#pragma unroll
    for (int l = 0; l < N_CLS; ++l) {
        v[l] = h * wv[l];
        v[l] += __shfl_xor(v[l], 1, 64); v[l] += __shfl_xor(v[l], 2, 64);
        v[l] += __shfl_xor(v[l], 4, 64); v[l] += __shfl_xor(v[l], 8, 64);
        v[l] += __shfl_xor(v[l], 16, 64); v[l] += __shfl_xor(v[l], 32, 64);
    }
    if (lane == 0) {
#pragma unroll
        for (int l = 0; l < N_CLS; ++l) cpart[w][l] = v[l];
    }
    __syncthreads();
    if (tid == 0) {
        float lg[N_CLS];
#pragma unroll
        for (int l = 0; l < N_CLS; ++l)
            lg[l] = cpart[0][l] + cpart[1][l] + cpart[2][l] + cpart[3][l] + bcls[l];
        int best = 0;
#pragma unroll
        for (int l = 1; l < N_CLS; ++l) if (lg[l] > lg[best]) best = l;
        float Sv = 1.f;
#pragma unroll
        for (int l = 0; l < N_CLS; ++l) {
            float hz = 1.f / (1.f + expf(-lg[l]));
            out[l] = hz;
            Sv *= (1.f - hz);
            out[4 + l] = Sv;
        }
        out[8] = (float)best;
    }
}

extern "C" void kernel_launch(void* const* d_in, const int* in_sizes, int n_in,
                              void* d_out, int out_size, void* d_ws, size_t ws_size,
                              hipStream_t stream)
{
    const float* x    = (const float*)d_in[0];
    const int*   cid  = (const int*)d_in[1];
    const float* W1   = (const float*)d_in[2];
    const float* b1   = (const float*)d_in[3];
    const float* W2   = (const float*)d_in[4];
    const float* b2   = (const float*)d_in[5];
    const float* Wfc  = (const float*)d_in[6];
    const float* bfc  = (const float*)d_in[7];
    const float* Wa   = (const float*)d_in[8];
    const float* ba   = (const float*)d_in[9];
    const float* Wb   = (const float*)d_in[10];
    const float* bb   = (const float*)d_in[11];
    const float* Wc   = (const float*)d_in[12];
    const float* bc   = (const float*)d_in[13];
    const float* Wrho = (const float*)d_in[14];
    const float* brho = (const float*)d_in[15];
    const float* Wcls = (const float*)d_in[16];
    const float* bcls = (const float*)d_in[17];
    float* out = (float*)d_out;

    int n = in_sizes[0] / D_IN;                       // 20000
    int rowTiles = (n + BM - 1) / BM + C_NUM;         // worst-case tiles (167)
    int npadMax = rowTiles * BM;

    // workspace layout
    char* w = (char*)d_ws;
    int* counts   = (int*)w;                          // [16]
    float* scores = (float*)(counts + 16);            // [16]
    float* hr_raw = scores + 16;                      // [256]
    float* pooled = hr_raw + 256;                     // [5120]
    size_t zero_bytes = (size_t)(16 + 16 + 256 + 5120) * 4;
    int* aoff   = (int*)(pooled + 5120);              // [16]
    float* hfc  = (float*)(aoff + 16);                // [5120]
    int* bucket = (int*)(hfc + 5120);                 // [npadMax]
    short* Wt1 = (short*)(bucket + npadMax);          // C*512*1024
    short* Wt2 = Wt1 + (size_t)C_NUM * D_H * D_IN;    // C*512*512
    short* h1  = Wt2 + (size_t)C_NUM * D_H * D_H;     // npadMax*512
    short* xbl = h1 + (size_t)npadMax * D_H;          // n*1024 (big path)
    size_t need_big = (size_t)((char*)(xbl + (size_t)n * D_IN) - w);
    bool big = ws_size >= need_big;

    hipMemsetAsync(w, 0, zero_bytes, stream);

    k_bucket<<<1, 1024, 0, stream>>>(cid, n, counts, aoff, bucket);
    k_transpose2<<<C_NUM * 128 + C_NUM * 64, 256, 0, stream>>>(W1, Wt1, W2, Wt2);

    if (big) {
        k_convertlin<<<(n * D_IN / 8 + 255) / 256, 256, 0, stream>>>(x, xbl);
        k_gemm1g<<<rowTiles * 4, 256, 0, stream>>>(xbl, Wt1, b1, bucket, aoff, h1);
    } else {
        k_gemm1f<<<dim3(rowTiles, 4), 256, 0, stream>>>(x, Wt1, b1, bucket, aoff, h1);
    }
    k_gemm2_mfma<<<rowTiles * 4, 256, 0, stream>>>(h1, Wt2, b2, bucket, aoff, pooled);

    k_tA<<<8, 256, 0, stream>>>(pooled, counts, Wfc, bfc, hfc);
    k_tB<<<4, 256, 0, stream>>>(hfc, Wa, ba, Wb, bb, Wc, scores);
    k_tCD<<<16, 256, 0, stream>>>(scores, bc, hfc, Wrho, hr_raw);
    k_tE<<<1, 256, 0, stream>>>(hr_raw, brho, Wcls, bcls, out);
}

// Round 7
// 138.973 us; speedup vs baseline: 1.4618x; 1.4618x over previous
//
#include <hip/hip_runtime.h>
#include <hip/hip_bf16.h>
#include <math.h>

// MIL_Cluster_FC round 7:
//  - REVERT bucketing to R4's multi-block LDS-aggregated hist/offsets/scatter
//    (R6's single-block k_bucket was 67us @ 1 CU; multi-block was ~7us)
//  - keep R6: merged W1+W2 transpose, linear fp32->bf16 convert, in-GEMM
//    gather via per-lane global_load_lds source (m173)
//  - proven tail (tA/tB/tCD/tE), XCD swizzle on both GEMMs

#define C_NUM 10
#define D_IN 1024
#define D_H 512
#define D_ATT 256
#define N_CLS 4
#define BM 128
#define BN 128
#define BKS 64

typedef __attribute__((ext_vector_type(8))) short short8v;
typedef __attribute__((ext_vector_type(4))) short short4v;
typedef __attribute__((ext_vector_type(4))) float f32x4;

__device__ __forceinline__ short f2bf(float f) {
    __hip_bfloat16 h = __float2bfloat16(f);
    return *reinterpret_cast<short*>(&h);
}

__device__ __forceinline__ void gload_lds16(const void* g, void* l) {
    __builtin_amdgcn_global_load_lds((const __attribute__((address_space(1))) unsigned int*)g,
                                     (__attribute__((address_space(3))) unsigned int*)l,
                                     16, 0, 0);
}

// bijective XCD-chunked swizzle (m204)
__device__ __forceinline__ int xcd_swizzle(int orig, int nwg) {
    int q = nwg >> 3, r = nwg & 7;
    int xcd = orig & 7, base = orig >> 3;
    return (xcd < r ? xcd * (q + 1) : r * (q + 1) + (xcd - r) * q) + base;
}

// LDS-aggregated histogram (R4-proven)
__global__ __launch_bounds__(256) void k_hist(const int* __restrict__ cid, int* counts, int n) {
    __shared__ int lc[C_NUM];
    int tid = threadIdx.x;
    if (tid < C_NUM) lc[tid] = 0;
    __syncthreads();
    int i = blockIdx.x * 256 + tid;
    if (i < n) atomicAdd(&lc[cid[i]], 1);
    __syncthreads();
    if (tid < C_NUM && lc[tid] > 0) atomicAdd(&counts[tid], lc[tid]);
}

__global__ void k_offsets(const int* __restrict__ counts, int* aoff) {
    if (threadIdx.x == 0) {
        int off = 0;
        for (int c = 0; c < C_NUM; ++c) {
            aoff[c] = off;
            off += ((counts[c] + BM - 1) / BM) * BM;
        }
        aoff[C_NUM] = off;
    }
}

// LDS-aggregated scatter (R4-proven)
__global__ __launch_bounds__(256) void k_scatter(const int* __restrict__ cid, int* cursor,
                                                 const int* __restrict__ aoff, int* bucket, int n) {
    __shared__ int lc[C_NUM];
    __shared__ int base[C_NUM];
    int tid = threadIdx.x;
    if (tid < C_NUM) lc[tid] = 0;
    __syncthreads();
    int i = blockIdx.x * 256 + tid;
    int c = 0, lpos = 0;
    bool valid = (i < n);
    if (valid) { c = cid[i]; lpos = atomicAdd(&lc[c], 1); }
    __syncthreads();
    if (tid < C_NUM) base[tid] = (lc[tid] > 0) ? atomicAdd(&cursor[tid], lc[tid]) : 0;
    __syncthreads();
    if (valid) bucket[aoff[c] + base[c] + lpos] = i;
}

// linear fp32 -> bf16 cast of x (coalesced, no gather, no bucket dep)
__global__ __launch_bounds__(256) void k_convertlin(const float* __restrict__ x,
                                                    short* __restrict__ xbl) {
    size_t i = (size_t)blockIdx.x * 256 + threadIdx.x;
    const f32x4* p = (const f32x4*)(x + i * 8);
    f32x4 f0 = p[0], f1 = p[1];
    short8v v;
#pragma unroll
    for (int e = 0; e < 4; ++e) { v[e] = f2bf(f0[e]); v[4 + e] = f2bf(f1[e]); }
    *(short8v*)&xbl[i * 8] = v;
}

// merged W1+W2 transpose: [C][K][N] fp32 -> [C][N][K] bf16
__global__ __launch_bounds__(256) void k_transpose2(
    const float* __restrict__ W1, short* __restrict__ Wt1,
    const float* __restrict__ W2, short* __restrict__ Wt2)
{
    __shared__ float t[64][65];
    int bid = blockIdx.x;
    const float* src; short* dst; int K, N, k0, n0;
    if (bid < C_NUM * 128) {            // W1: K=1024 (16 blk) x N=512 (8 blk)
        int cc = bid >> 7, r = bid & 127;
        k0 = (r & 15) * 64; n0 = (r >> 4) * 64;
        src = W1 + (size_t)cc * D_IN * D_H; dst = Wt1 + (size_t)cc * D_H * D_IN;
        K = D_IN; N = D_H;
    } else {                            // W2: K=512 (8 blk) x N=512 (8 blk)
        int idx = bid - C_NUM * 128;
        int cc = idx >> 6, r = idx & 63;
        k0 = (r & 7) * 64; n0 = (r >> 3) * 64;
        src = W2 + (size_t)cc * D_H * D_H; dst = Wt2 + (size_t)cc * D_H * D_H;
        K = D_H; N = D_H;
    }
    int tid = threadIdx.x;
    int tk = tid >> 4, tn4 = (tid & 15) * 4;
#pragma unroll
    for (int it = 0; it < 4; ++it) {
        int k = tk + it * 16;
        f32x4 v = *(const f32x4*)&src[(size_t)(k0 + k) * N + n0 + tn4];
        t[k][tn4 + 0] = v[0]; t[k][tn4 + 1] = v[1];
        t[k][tn4 + 2] = v[2]; t[k][tn4 + 3] = v[3];
    }
    __syncthreads();
    int wn = tid >> 2, kq = (tid & 3) * 16;
#pragma unroll
    for (int q = 0; q < 4; ++q) {
        int k = kq + q * 4;
        short4v o;
#pragma unroll
        for (int e = 0; e < 4; ++e) o[e] = f2bf(t[k + e][wn]);
        *(short4v*)&dst[(size_t)(n0 + wn) * K + k0 + k] = o;
    }
}

// gemm1 (gathered): h1 = relu(xbl[bucket] @ W1t^T + b1); A gathered via
// per-lane global_load_lds source addresses, linear LDS dest, XOR slot swizzle.
__global__ __launch_bounds__(256) void k_gemm1g(
    const short* __restrict__ xbl, const short* __restrict__ Wt, const float* __restrict__ b1,
    const int* __restrict__ bucket, const int* __restrict__ aoff, short* __restrict__ h1)
{
    __shared__ short As[BM * BKS];
    __shared__ short Bs[BN * BKS];
    __shared__ int ridx[BM];

    int wg = xcd_swizzle(blockIdx.x, gridDim.x);
    int rowStart = (wg >> 2) * BM;
    if (rowStart >= aoff[C_NUM]) return;
    int c = 0;
    while (c < C_NUM - 1 && rowStart >= aoff[c + 1]) ++c;
    int colStart = (wg & 3) * BN;

    int tid = threadIdx.x;
    int lane = tid & 63;
    int wid = tid >> 6;
    int wm = wid >> 1, wn = wid & 1;

    if (tid < BM) ridx[tid] = bucket[rowStart + tid];
    __syncthreads();

    int l8 = lane >> 3;
    int sslot = (lane & 7) ^ l8;
    // per-lane gathered A-row base for each staging quarter
    const short* aq[4];
#pragma unroll
    for (int q = 0; q < 4; ++q) {
        int rr = ridx[(q * 4 + wid) * 8 + l8];
        aq[q] = xbl + (size_t)(rr < 0 ? 0 : rr) * D_IN + sslot * 8;
    }
    const short* bbase = Wt + ((size_t)c * D_H + colStart + l8) * D_IN + sslot * 8;

    f32x4 acc[4][4];
#pragma unroll
    for (int i = 0; i < 4; ++i)
#pragma unroll
        for (int j = 0; j < 4; ++j)
            acc[i][j] = f32x4{0.f, 0.f, 0.f, 0.f};

    for (int k0 = 0; k0 < D_IN; k0 += BKS) {
#pragma unroll
        for (int q = 0; q < 4; ++q) {
            int rb = (q * 4 + wid) * 8;
            gload_lds16(aq[q] + k0, &As[rb * BKS]);
            gload_lds16(bbase + (size_t)rb * D_IN + k0, &Bs[rb * BKS]);
        }
        __syncthreads();
#pragma unroll
        for (int kk = 0; kk < 2; ++kk) {
            short8v af[4], bfr[4];
#pragma unroll
            for (int i = 0; i < 4; ++i) {
                int row = wm * 64 + i * 16 + (lane & 15);
                int slot = (kk * 4 + (lane >> 4)) ^ (row & 7);
                af[i] = *(const short8v*)&As[row * BKS + slot * 8];
            }
#pragma unroll
            for (int j = 0; j < 4; ++j) {
                int nn = wn * 64 + j * 16 + (lane & 15);
                int slot = (kk * 4 + (lane >> 4)) ^ (nn & 7);
                bfr[j] = *(const short8v*)&Bs[nn * BKS + slot * 8];
            }
#pragma unroll
            for (int i = 0; i < 4; ++i)
#pragma unroll
                for (int j = 0; j < 4; ++j)
                    acc[i][j] = __builtin_amdgcn_mfma_f32_16x16x32_bf16(af[i], bfr[j], acc[i][j], 0, 0, 0);
        }
        __syncthreads();
    }

    const float* bias = b1 + c * D_H;
    float bj[4];
#pragma unroll
    for (int j = 0; j < 4; ++j) bj[j] = bias[colStart + wn * 64 + j * 16 + (lane & 15)];
#pragma unroll
    for (int i = 0; i < 4; ++i) {
#pragma unroll
        for (int r = 0; r < 4; ++r) {
            int rowl = wm * 64 + i * 16 + (lane >> 4) * 4 + r;
            bool valid = (ridx[rowl] >= 0);
            size_t gro = (size_t)(rowStart + rowl) * D_H + colStart + wn * 64 + (lane & 15);
#pragma unroll
            for (int j = 0; j < 4; ++j) {
                float v = valid ? fmaxf(acc[i][j][r] + bj[j], 0.f) : 0.f;
                h1[gro + j * 16] = f2bf(v);
            }
        }
    }
}

// gemm1 fallback (small ws): reg-staged fp32 x -> bf16
__global__ __launch_bounds__(256) void k_gemm1f(
    const float* __restrict__ x, const short* __restrict__ Wt, const float* __restrict__ b1,
    const int* __restrict__ bucket, const int* __restrict__ aoff, short* __restrict__ h1)
{
    __shared__ short As[BM * BKS];
    __shared__ short Bs[BN * BKS];
    __shared__ int ridx[BM];

    int rowStart = blockIdx.x * BM;
    if (rowStart >= aoff[C_NUM]) return;
    int c = 0;
    while (c < C_NUM - 1 && rowStart >= aoff[c + 1]) ++c;
    int colStart = blockIdx.y * BN;

    int tid = threadIdx.x;
    int lane = tid & 63;
    int wid = tid >> 6;
    int wm = wid >> 1, wn = wid & 1;

    if (tid < BM) ridx[tid] = bucket[rowStart + tid];
    __syncthreads();

    int arow = tid >> 1;
    int khalf = tid & 1;
    int agr = ridx[arow];
    const float* aptr = x + (size_t)(agr < 0 ? 0 : agr) * D_IN + khalf * 32;

    int l8 = lane >> 3;
    int sslot = (lane & 7) ^ l8;
    const short* bbase = Wt + ((size_t)c * D_H + colStart + l8) * D_IN + sslot * 8;

    f32x4 acc[4][4];
#pragma unroll
    for (int i = 0; i < 4; ++i)
#pragma unroll
        for (int j = 0; j < 4; ++j)
            acc[i][j] = f32x4{0.f, 0.f, 0.f, 0.f};

    for (int k0 = 0; k0 < D_IN; k0 += BKS) {
#pragma unroll
        for (int q = 0; q < 4; ++q) {
            int nbase = (q * 4 + wid) * 8;
            gload_lds16(bbase + (size_t)nbase * D_IN + k0, &Bs[nbase * BKS]);
        }
        {
            const f32x4* p = (const f32x4*)(aptr + k0);
#pragma unroll
            for (int q = 0; q < 4; ++q) {
                f32x4 f0 = {0.f, 0.f, 0.f, 0.f}, f1 = {0.f, 0.f, 0.f, 0.f};
                if (agr >= 0) { f0 = p[2 * q]; f1 = p[2 * q + 1]; }
                short8v v;
#pragma unroll
                for (int e = 0; e < 4; ++e) { v[e] = f2bf(f0[e]); v[4 + e] = f2bf(f1[e]); }
                int slot = (khalf * 4 + q) ^ (arow & 7);
                *(short8v*)&As[arow * BKS + slot * 8] = v;
            }
        }
        __syncthreads();
#pragma unroll
        for (int kk = 0; kk < 2; ++kk) {
            short8v af[4], bfr[4];
#pragma unroll
            for (int i = 0; i < 4; ++i) {
                int row = wm * 64 + i * 16 + (lane & 15);
                int slot = (kk * 4 + (lane >> 4)) ^ (row & 7);
                af[i] = *(const short8v*)&As[row * BKS + slot * 8];
            }
#pragma unroll
            for (int j = 0; j < 4; ++j) {
                int nn = wn * 64 + j * 16 + (lane & 15);
                int slot = (kk * 4 + (lane >> 4)) ^ (nn & 7);
                bfr[j] = *(const short8v*)&Bs[nn * BKS + slot * 8];
            }
#pragma unroll
            for (int i = 0; i < 4; ++i)
#pragma unroll
                for (int j = 0; j < 4; ++j)
                    acc[i][j] = __builtin_amdgcn_mfma_f32_16x16x32_bf16(af[i], bfr[j], acc[i][j], 0, 0, 0);
        }
        __syncthreads();
    }

    const float* bias = b1 + c * D_H;
    float bj[4];
#pragma unroll
    for (int j = 0; j < 4; ++j) bj[j] = bias[colStart + wn * 64 + j * 16 + (lane & 15)];
#pragma unroll
    for (int i = 0; i < 4; ++i) {
#pragma unroll
        for (int r = 0; r < 4; ++r) {
            int rowl = wm * 64 + i * 16 + (lane >> 4) * 4 + r;
            bool valid = (ridx[rowl] >= 0);
            size_t gro = (size_t)(rowStart + rowl) * D_H + colStart + wn * 64 + (lane & 15);
#pragma unroll
            for (int j = 0; j < 4; ++j) {
                float v = valid ? fmaxf(acc[i][j][r] + bj[j], 0.f) : 0.f;
                h1[gro + j * 16] = f2bf(v);
            }
        }
    }
}

// pooled[c,:] += column-sum over real rows of relu(h1 @ W2[c] + b2[c])
__global__ __launch_bounds__(256) void k_gemm2_mfma(
    const short* __restrict__ h1, const short* __restrict__ Wt, const float* __restrict__ b2,
    const int* __restrict__ bucket, const int* __restrict__ aoff, float* __restrict__ pooled)
{
    __shared__ short As[BM * BKS];
    __shared__ short Bs[BN * BKS];
    __shared__ int ridx[BM];

    int wg = xcd_swizzle(blockIdx.x, gridDim.x);
    int rowStart = (wg >> 2) * BM;
    if (rowStart >= aoff[C_NUM]) return;
    int c = 0;
    while (c < C_NUM - 1 && rowStart >= aoff[c + 1]) ++c;
    int colStart = (wg & 3) * BN;

    int tid = threadIdx.x;
    int lane = tid & 63;
    int wid = tid >> 6;
    int wm = wid >> 1, wn = wid & 1;

    if (tid < BM) ridx[tid] = bucket[rowStart + tid];

    int l8 = lane >> 3;
    int sslot = (lane & 7) ^ l8;
    const short* abase = h1 + (size_t)(rowStart + l8) * D_H + sslot * 8;
    const short* bbase = Wt + ((size_t)c * D_H + colStart + l8) * D_H + sslot * 8;

    f32x4 acc[4][4];
#pragma unroll
    for (int i = 0; i < 4; ++i)
#pragma unroll
        for (int j = 0; j < 4; ++j)
            acc[i][j] = f32x4{0.f, 0.f, 0.f, 0.f};

    for (int k0 = 0; k0 < D_H; k0 += BKS) {
#pragma unroll
        for (int q = 0; q < 4; ++q) {
            int rb = (q * 4 + wid) * 8;
            gload_lds16(abase + (size_t)rb * D_H + k0, &As[rb * BKS]);
            gload_lds16(bbase + (size_t)rb * D_H + k0, &Bs[rb * BKS]);
        }
        __syncthreads();
#pragma unroll
        for (int kk = 0; kk < 2; ++kk) {
            short8v af[4], bfr[4];
#pragma unroll
            for (int i = 0; i < 4; ++i) {
                int row = wm * 64 + i * 16 + (lane & 15);
                int slot = (kk * 4 + (lane >> 4)) ^ (row & 7);
                af[i] = *(const short8v*)&As[row * BKS + slot * 8];
            }
#pragma unroll
            for (int j = 0; j < 4; ++j) {
                int nn = wn * 64 + j * 16 + (lane & 15);
                int slot = (kk * 4 + (lane >> 4)) ^ (nn & 7);
                bfr[j] = *(const short8v*)&Bs[nn * BKS + slot * 8];
            }
#pragma unroll
            for (int i = 0; i < 4; ++i)
#pragma unroll
                for (int j = 0; j < 4; ++j)
                    acc[i][j] = __builtin_amdgcn_mfma_f32_16x16x32_bf16(af[i], bfr[j], acc[i][j], 0, 0, 0);
        }
        __syncthreads();
    }

    const float* bias = b2 + c * D_H;
    float bj[4];
#pragma unroll
    for (int j = 0; j < 4; ++j) bj[j] = bias[colStart + wn * 64 + j * 16 + (lane & 15)];
    float csum[4] = {0.f, 0.f, 0.f, 0.f};
#pragma unroll
    for (int i = 0; i < 4; ++i) {
#pragma unroll
        for (int r = 0; r < 4; ++r) {
            int rowl = wm * 64 + i * 16 + (lane >> 4) * 4 + r;
            float m = (ridx[rowl] >= 0) ? 1.f : 0.f;
#pragma unroll
            for (int j = 0; j < 4; ++j)
                csum[j] += m * fmaxf(acc[i][j][r] + bj[j], 0.f);
        }
    }
#pragma unroll
    for (int j = 0; j < 4; ++j) {
        float s = csum[j];
        s += __shfl_xor(s, 16, 64);
        s += __shfl_xor(s, 32, 64);
        if ((lane >> 4) == 0)
            atomicAdd(&pooled[c * D_H + colStart + wn * 64 + j * 16 + lane], s);
    }
}

// ---- tail stage A ----
__global__ __launch_bounds__(256) void k_tA(
    const float* __restrict__ pooled, const int* __restrict__ counts,
    const float* __restrict__ Wfc, const float* __restrict__ bfc,
    float* __restrict__ hfc)
{
    __shared__ float hcs[C_NUM][D_H];
    __shared__ float red[4][64][C_NUM];
    int tid = threadIdx.x;
    for (int idx = tid; idx < C_NUM * D_H; idx += 256) {
        int cc = idx >> 9;
        hcs[cc][idx & (D_H - 1)] = pooled[idx] / fmaxf((float)counts[cc], 1.f);
    }
    __syncthreads();
    int col = blockIdx.x * 64 + (tid & 63);
    int kq = tid >> 6, k0 = kq * 128;
    float acc[C_NUM] = {};
    for (int k = 0; k < 128; ++k) {
        float wv = Wfc[(size_t)(k0 + k) * D_H + col];
#pragma unroll
        for (int cc = 0; cc < C_NUM; ++cc) acc[cc] += hcs[cc][k0 + k] * wv;
    }
#pragma unroll
    for (int cc = 0; cc < C_NUM; ++cc) red[kq][tid & 63][cc] = acc[cc];
    __syncthreads();
    if (kq == 0) {
        float bv = bfc[col];
#pragma unroll
        for (int cc = 0; cc < C_NUM; ++cc) {
            float s = red[0][tid][cc] + red[1][tid][cc] + red[2][tid][cc] + red[3][tid][cc];
            hfc[cc * D_H + col] = fmaxf(s + bv, 0.f);
        }
    }
}

// ---- tail stage B ----
__global__ __launch_bounds__(256) void k_tB(
    const float* __restrict__ hfc,
    const float* __restrict__ Wa, const float* __restrict__ ba,
    const float* __restrict__ Wb, const float* __restrict__ bb,
    const float* __restrict__ Wc,
    float* __restrict__ scores)
{
    __shared__ float hfs[C_NUM][D_H];
    __shared__ float red[4][64][C_NUM][2];
    int tid = threadIdx.x;
    for (int idx = tid; idx < C_NUM * D_H; idx += 256) {
        hfs[idx >> 9][idx & (D_H - 1)] = hfc[idx];
    }
    __syncthreads();
    int ad = blockIdx.x * 64 + (tid & 63);
    int kq = tid >> 6, k0 = kq * 128;
    float sa[C_NUM] = {}, sb[C_NUM] = {};
    for (int k = 0; k < 128; ++k) {
        float wav = Wa[(size_t)(k0 + k) * D_ATT + ad];
        float wbv = Wb[(size_t)(k0 + k) * D_ATT + ad];
#pragma unroll
        for (int cc = 0; cc < C_NUM; ++cc) {
            float h = hfs[cc][k0 + k];
            sa[cc] += h * wav;
            sb[cc] += h * wbv;
        }
    }
#pragma unroll
    for (int cc = 0; cc < C_NUM; ++cc) {
        red[kq][tid & 63][cc][0] = sa[cc];
        red[kq][tid & 63][cc][1] = sb[cc];
    }
    __syncthreads();
    if (kq == 0) {
        float bav = ba[ad], bbv = bb[ad], wcv = Wc[ad];
#pragma unroll
        for (int cc = 0; cc < C_NUM; ++cc) {
            float sat = red[0][tid][cc][0] + red[1][tid][cc][0] + red[2][tid][cc][0] + red[3][tid][cc][0];
            float sbt = red[0][tid][cc][1] + red[1][tid][cc][1] + red[2][tid][cc][1] + red[3][tid][cc][1];
            float v = tanhf(sat + bav) * (1.f / (1.f + expf(-(sbt + bbv)))) * wcv;
            v += __shfl_xor(v, 1, 64); v += __shfl_xor(v, 2, 64); v += __shfl_xor(v, 4, 64);
            v += __shfl_xor(v, 8, 64); v += __shfl_xor(v, 16, 64); v += __shfl_xor(v, 32, 64);
            if (tid == 0) atomicAdd(&scores[cc], v);
        }
    }
}

// ---- tail stage C+D fused ----
__global__ __launch_bounds__(256) void k_tCD(
    const float* __restrict__ scores, const float* __restrict__ bc,
    const float* __restrict__ hfc, const float* __restrict__ Wrho,
    float* __restrict__ hr_raw)
{
    __shared__ float hps[32];
    int tid = threadIdx.x;
    int k0 = blockIdx.x * 32;
    if (tid < 32) {
        float sc2[C_NUM];
        float mx = -1e30f;
#pragma unroll
        for (int cc = 0; cc < C_NUM; ++cc) { sc2[cc] = scores[cc] + bc[0]; mx = fmaxf(mx, sc2[cc]); }
        float sum = 0.f;
#pragma unroll
        for (int cc = 0; cc < C_NUM; ++cc) { sc2[cc] = expf(sc2[cc] - mx); sum += sc2[cc]; }
        float s = 0.f;
#pragma unroll
        for (int cc = 0; cc < C_NUM; ++cc) s += (sc2[cc] / sum) * hfc[cc * D_H + k0 + tid];
        hps[tid] = s;
    }
    __syncthreads();
    float acc = 0.f;
#pragma unroll 8
    for (int k = 0; k < 32; ++k)
        acc += hps[k] * Wrho[(size_t)(k0 + k) * D_ATT + tid];
    atomicAdd(&hr_raw[tid], acc);
}

// ---- tail stage E ----
__global__ __launch_bounds__(256) void k_tE(
    const float* __restrict__ hr_raw, const float* __restrict__ brho,
    const float* __restrict__ Wcls, const float* __restrict__ bcls,
    float* __restrict__ out)
{
    __shared__ float cpart[4][N_CLS];
    int tid = threadIdx.x, lane = tid & 63, w = tid >> 6;
    float h = fmaxf(hr_raw[tid] + brho[tid], 0.f);
    f32x4 wv = *(const f32x4*)&Wcls[tid * N_CLS];
    float v[N_CLS];
#pragma unroll
    for (int l = 0; l < N_CLS; ++l) {
        v[l] = h * wv[l];
        v[l] += __shfl_xor(v[l], 1, 64); v[l] += __shfl_xor(v[l], 2, 64);
        v[l] += __shfl_xor(v[l], 4, 64); v[l] += __shfl_xor(v[l], 8, 64);
        v[l] += __shfl_xor(v[l], 16, 64); v[l] += __shfl_xor(v[l], 32, 64);
    }
    if (lane == 0) {
#pragma unroll
        for (int l = 0; l < N_CLS; ++l) cpart[w][l] = v[l];
    }
    __syncthreads();
    if (tid == 0) {
        float lg[N_CLS];
#pragma unroll
        for (int l = 0; l < N_CLS; ++l)
            lg[l] = cpart[0][l] + cpart[1][l] + cpart[2][l] + cpart[3][l] + bcls[l];
        int best = 0;
#pragma unroll
        for (int l = 1; l < N_CLS; ++l) if (lg[l] > lg[best]) best = l;
        float Sv = 1.f;
#pragma unroll
        for (int l = 0; l < N_CLS; ++l) {
            float hz = 1.f / (1.f + expf(-lg[l]));
            out[l] = hz;
            Sv *= (1.f - hz);
            out[4 + l] = Sv;
        }
        out[8] = (float)best;
    }
}

extern "C" void kernel_launch(void* const* d_in, const int* in_sizes, int n_in,
                              void* d_out, int out_size, void* d_ws, size_t ws_size,
                              hipStream_t stream)
{
    const float* x    = (const float*)d_in[0];
    const int*   cid  = (const int*)d_in[1];
    const float* W1   = (const float*)d_in[2];
    const float* b1   = (const float*)d_in[3];
    const float* W2   = (const float*)d_in[4];
    const float* b2   = (const float*)d_in[5];
    const float* Wfc  = (const float*)d_in[6];
    const float* bfc  = (const float*)d_in[7];
    const float* Wa   = (const float*)d_in[8];
    const float* ba   = (const float*)d_in[9];
    const float* Wb   = (const float*)d_in[10];
    const float* bb   = (const float*)d_in[11];
    const float* Wc   = (const float*)d_in[12];
    const float* bc   = (const float*)d_in[13];
    const float* Wrho = (const float*)d_in[14];
    const float* brho = (const float*)d_in[15];
    const float* Wcls = (const float*)d_in[16];
    const float* bcls = (const float*)d_in[17];
    float* out = (float*)d_out;

    int n = in_sizes[0] / D_IN;                       // 20000
    int rowTiles = (n + BM - 1) / BM + C_NUM;         // worst-case tiles (167)
    int npadMax = rowTiles * BM;

    // workspace layout
    char* w = (char*)d_ws;
    int* counts   = (int*)w;                          // [16]
    int* cursor   = counts + 16;                      // [16]
    float* scores = (float*)(counts + 32);            // [16]
    float* hr_raw = scores + 16;                      // [256]
    float* pooled = hr_raw + 256;                     // [5120]
    size_t zero_bytes = (size_t)(16 + 16 + 16 + 256 + 5120) * 4;
    int* aoff   = (int*)(pooled + 5120);              // [16]
    float* hfc  = (float*)(aoff + 16);                // [5120]
    int* bucket = (int*)(hfc + 5120);                 // [npadMax]
    short* Wt1 = (short*)(bucket + npadMax);          // C*512*1024
    short* Wt2 = Wt1 + (size_t)C_NUM * D_H * D_IN;    // C*512*512
    short* h1  = Wt2 + (size_t)C_NUM * D_H * D_H;     // npadMax*512
    short* xbl = h1 + (size_t)npadMax * D_H;          // n*1024 (big path)
    size_t need_big = (size_t)((char*)(xbl + (size_t)n * D_IN) - w);
    bool big = ws_size >= need_big;

    hipMemsetAsync(w, 0, zero_bytes, stream);
    hipMemsetAsync(bucket, 0xFF, (size_t)npadMax * 4, stream);  // -1 sentinels

    int nb = (n + 255) / 256;
    k_hist<<<nb, 256, 0, stream>>>(cid, counts, n);
    k_offsets<<<1, 64, 0, stream>>>(counts, aoff);
    k_scatter<<<nb, 256, 0, stream>>>(cid, cursor, aoff, bucket, n);

    k_transpose2<<<C_NUM * 128 + C_NUM * 64, 256, 0, stream>>>(W1, Wt1, W2, Wt2);

    if (big) {
        k_convertlin<<<(n * D_IN / 8 + 255) / 256, 256, 0, stream>>>(x, xbl);
        k_gemm1g<<<rowTiles * 4, 256, 0, stream>>>(xbl, Wt1, b1, bucket, aoff, h1);
    } else {
        k_gemm1f<<<dim3(rowTiles, 4), 256, 0, stream>>>(x, Wt1, b1, bucket, aoff, h1);
    }
    k_gemm2_mfma<<<rowTiles * 4, 256, 0, stream>>>(h1, Wt2, b2, bucket, aoff, pooled);

    k_tA<<<8, 256, 0, stream>>>(pooled, counts, Wfc, bfc, hfc);
    k_tB<<<4, 256, 0, stream>>>(hfc, Wa, ba, Wb, bb, Wc, scores);
    k_tCD<<<16, 256, 0, stream>>>(scores, bc, hfc, Wrho, hr_raw);
    k_tE<<<1, 256, 0, stream>>>(hr_raw, brho, Wcls, bcls, out);
}

// Round 8
// 124.354 us; speedup vs baseline: 1.6337x; 1.1176x over previous
//
#include <hip/hip_runtime.h>
#include <hip/hip_bf16.h>
#include <math.h>

// MIL_Cluster_FC round 8:
//  - k_convertlin REMOVED: gemm1 stages fp32 x directly via global_load_lds
//    (async; R5's failure was synchronous reg-staging) into 32KB fp32 LDS
//    tile, XOR-swizzled 16B slots (2-way alias = free), fp32->bf16 cvt at
//    fragment read (VALU headroom exists; MFMA util ~15-20%)
//  - dispatch-count diet: offsets+pad-memset folded into k_scatter; GEMMs
//    compute aoff locally from counts; tE merged into tCD (last-block-done)
//  - 14 dispatches -> 10

#define C_NUM 10
#define D_IN 1024
#define D_H 512
#define D_ATT 256
#define N_CLS 4
#define BM 128
#define BN 128
#define BKS 64

typedef __attribute__((ext_vector_type(8))) short short8v;
typedef __attribute__((ext_vector_type(4))) short short4v;
typedef __attribute__((ext_vector_type(4))) float f32x4;

__device__ __forceinline__ short f2bf(float f) {
    __hip_bfloat16 h = __float2bfloat16(f);
    return *reinterpret_cast<short*>(&h);
}

__device__ __forceinline__ void gload_lds16(const void* g, void* l) {
    __builtin_amdgcn_global_load_lds((const __attribute__((address_space(1))) unsigned int*)g,
                                     (__attribute__((address_space(3))) unsigned int*)l,
                                     16, 0, 0);
}

// bijective XCD-chunked swizzle (m204)
__device__ __forceinline__ int xcd_swizzle(int orig, int nwg) {
    int q = nwg >> 3, r = nwg & 7;
    int xcd = orig & 7, base = orig >> 3;
    return (xcd < r ? xcd * (q + 1) : r * (q + 1) + (xcd - r) * q) + base;
}

// LDS-aggregated histogram
__global__ __launch_bounds__(256) void k_hist(const int* __restrict__ cid, int* counts, int n) {
    __shared__ int lc[C_NUM];
    int tid = threadIdx.x;
    if (tid < C_NUM) lc[tid] = 0;
    __syncthreads();
    int i = blockIdx.x * 256 + tid;
    if (i < n) atomicAdd(&lc[cid[i]], 1);
    __syncthreads();
    if (tid < C_NUM && lc[tid] > 0) atomicAdd(&counts[tid], lc[tid]);
}

// LDS-aggregated scatter + local prefix offsets + pad fill (block 0)
__global__ __launch_bounds__(256) void k_scatter(const int* __restrict__ cid, int* cursor,
                                                 const int* __restrict__ counts,
                                                 int* bucket, int n) {
    __shared__ int lc[C_NUM];
    __shared__ int basev[C_NUM];
    __shared__ int loff[C_NUM + 1];
    int tid = threadIdx.x;
    if (tid < C_NUM) lc[tid] = 0;
    if (tid == 0) {
        int off = 0;
        for (int c2 = 0; c2 < C_NUM; ++c2) {
            loff[c2] = off;
            off += ((counts[c2] + BM - 1) / BM) * BM;
        }
        loff[C_NUM] = off;
    }
    __syncthreads();
    int i = blockIdx.x * 256 + tid;
    int c = 0, lpos = 0;
    bool valid = (i < n);
    if (valid) { c = cid[i]; lpos = atomicAdd(&lc[c], 1); }
    __syncthreads();
    if (tid < C_NUM) basev[tid] = (lc[tid] > 0) ? atomicAdd(&cursor[tid], lc[tid]) : 0;
    __syncthreads();
    if (valid) bucket[loff[c] + basev[c] + lpos] = i;
    if (blockIdx.x == 0) {  // pad slots -> -1 (disjoint from real slots)
        for (int c2 = 0; c2 < C_NUM; ++c2)
            for (int p = loff[c2] + counts[c2] + tid; p < loff[c2 + 1]; p += 256)
                bucket[p] = -1;
    }
}

// merged W1+W2 transpose: [C][K][N] fp32 -> [C][N][K] bf16
__global__ __launch_bounds__(256) void k_transpose2(
    const float* __restrict__ W1, short* __restrict__ Wt1,
    const float* __restrict__ W2, short* __restrict__ Wt2)
{
    __shared__ float t[64][65];
    int bid = blockIdx.x;
    const float* src; short* dst; int K, N, k0, n0;
    if (bid < C_NUM * 128) {            // W1: 16 x 8 tiles per cluster
        int cc = bid >> 7, r = bid & 127;
        k0 = (r & 15) * 64; n0 = (r >> 4) * 64;
        src = W1 + (size_t)cc * D_IN * D_H; dst = Wt1 + (size_t)cc * D_H * D_IN;
        K = D_IN; N = D_H;
    } else {                            // W2: 8 x 8 tiles per cluster
        int idx = bid - C_NUM * 128;
        int cc = idx >> 6, r = idx & 63;
        k0 = (r & 7) * 64; n0 = (r >> 3) * 64;
        src = W2 + (size_t)cc * D_H * D_H; dst = Wt2 + (size_t)cc * D_H * D_H;
        K = D_H; N = D_H;
    }
    int tid = threadIdx.x;
    int tk = tid >> 4, tn4 = (tid & 15) * 4;
#pragma unroll
    for (int it = 0; it < 4; ++it) {
        int k = tk + it * 16;
        f32x4 v = *(const f32x4*)&src[(size_t)(k0 + k) * N + n0 + tn4];
        t[k][tn4 + 0] = v[0]; t[k][tn4 + 1] = v[1];
        t[k][tn4 + 2] = v[2]; t[k][tn4 + 3] = v[3];
    }
    __syncthreads();
    int wn = tid >> 2, kq = (tid & 3) * 16;
#pragma unroll
    for (int q = 0; q < 4; ++q) {
        int k = kq + q * 4;
        short4v o;
#pragma unroll
        for (int e = 0; e < 4; ++e) o[e] = f2bf(t[k + e][wn]);
        *(short4v*)&dst[(size_t)(n0 + wn) * K + k0 + k] = o;
    }
}

// gemm1: h1 = relu(x[bucket] @ W1t^T + b1). fp32 A staged ASYNC via
// global_load_lds (gathered per-lane source rows, XOR-swizzled 16B slots,
// linear LDS dest), fp32->bf16 cvt at fragment read. B bf16 as before.
__global__ __launch_bounds__(256) void k_gemm1x(
    const float* __restrict__ x, const short* __restrict__ Wt, const float* __restrict__ b1,
    const int* __restrict__ bucket, const int* __restrict__ counts, short* __restrict__ h1)
{
    __shared__ float Asf[BM * BKS];   // 32 KB fp32
    __shared__ short Bs[BN * BKS];    // 16 KB bf16
    __shared__ int ridx[BM];
    __shared__ int saoff[C_NUM + 1];

    int tid = threadIdx.x;
    if (tid == 0) {
        int off = 0;
        for (int c2 = 0; c2 < C_NUM; ++c2) {
            saoff[c2] = off;
            off += ((counts[c2] + BM - 1) / BM) * BM;
        }
        saoff[C_NUM] = off;
    }
    __syncthreads();

    int wg = xcd_swizzle(blockIdx.x, gridDim.x);
    int rowStart = (wg >> 2) * BM;
    if (rowStart >= saoff[C_NUM]) return;
    int c = 0;
    while (c < C_NUM - 1 && rowStart >= saoff[c + 1]) ++c;
    int colStart = (wg & 3) * BN;

    int lane = tid & 63;
    int wid = tid >> 6;
    int wm = wid >> 1, wn = wid & 1;

    if (tid < BM) ridx[tid] = bucket[rowStart + tid];
    __syncthreads();

    // A: 8 staging steps/K-tile; step q: rows q*16 + wid*4 + (lane>>4),
    // lane&15 -> physical 16B slot; source slot = phys ^ (row&15) (involution)
    const float* aq[8];
#pragma unroll
    for (int q = 0; q < 8; ++q) {
        int row = q * 16 + wid * 4 + (lane >> 4);
        int rr = ridx[row];
        int srcslot = (lane & 15) ^ (row & 15);
        aq[q] = x + (size_t)(rr < 0 ? 0 : rr) * D_IN + srcslot * 4;
    }
    int l8 = lane >> 3;
    int sslot = (lane & 7) ^ l8;
    const short* bbase = Wt + ((size_t)c * D_H + colStart + l8) * D_IN + sslot * 8;

    f32x4 acc[4][4];
#pragma unroll
    for (int i = 0; i < 4; ++i)
#pragma unroll
        for (int j = 0; j < 4; ++j)
            acc[i][j] = f32x4{0.f, 0.f, 0.f, 0.f};

    for (int k0 = 0; k0 < D_IN; k0 += BKS) {
#pragma unroll
        for (int q = 0; q < 4; ++q) {
            int rb = (q * 4 + wid) * 8;
            gload_lds16(bbase + (size_t)rb * D_IN + k0, &Bs[rb * BKS]);
        }
#pragma unroll
        for (int q = 0; q < 8; ++q)
            gload_lds16(aq[q] + k0, &Asf[(q * 16 + wid * 4) * BKS]);
        __syncthreads();
#pragma unroll
        for (int kk = 0; kk < 2; ++kk) {
            short8v af[4], bfr[4];
#pragma unroll
            for (int i = 0; i < 4; ++i) {
                int row = wm * 64 + i * 16 + (lane & 15);
                int s8 = kk * 4 + (lane >> 4);
                int p0 = (2 * s8) ^ (row & 15);
                int p1 = (2 * s8 + 1) ^ (row & 15);
                f32x4 lo = *(const f32x4*)&Asf[row * BKS + p0 * 4];
                f32x4 hi = *(const f32x4*)&Asf[row * BKS + p1 * 4];
                short8v v;
#pragma unroll
                for (int e = 0; e < 4; ++e) { v[e] = f2bf(lo[e]); v[4 + e] = f2bf(hi[e]); }
                af[i] = v;
            }
#pragma unroll
            for (int j = 0; j < 4; ++j) {
                int nn = wn * 64 + j * 16 + (lane & 15);
                int slot = (kk * 4 + (lane >> 4)) ^ (nn & 7);
                bfr[j] = *(const short8v*)&Bs[nn * BKS + slot * 8];
            }
#pragma unroll
            for (int i = 0; i < 4; ++i)
#pragma unroll
                for (int j = 0; j < 4; ++j)
                    acc[i][j] = __builtin_amdgcn_mfma_f32_16x16x32_bf16(af[i], bfr[j], acc[i][j], 0, 0, 0);
        }
        __syncthreads();
    }

    const float* bias = b1 + c * D_H;
    float bj[4];
#pragma unroll
    for (int j = 0; j < 4; ++j) bj[j] = bias[colStart + wn * 64 + j * 16 + (lane & 15)];
#pragma unroll
    for (int i = 0; i < 4; ++i) {
#pragma unroll
        for (int r = 0; r < 4; ++r) {
            int rowl = wm * 64 + i * 16 + (lane >> 4) * 4 + r;
            bool valid = (ridx[rowl] >= 0);
            size_t gro = (size_t)(rowStart + rowl) * D_H + colStart + wn * 64 + (lane & 15);
#pragma unroll
            for (int j = 0; j < 4; ++j) {
                float v = valid ? fmaxf(acc[i][j][r] + bj[j], 0.f) : 0.f;
                h1[gro + j * 16] = f2bf(v);
            }
        }
    }
}

// pooled[c,:] += column-sum over real rows of relu(h1 @ W2[c] + b2[c])
__global__ __launch_bounds__(256) void k_gemm2_mfma(
    const short* __restrict__ h1, const short* __restrict__ Wt, const float* __restrict__ b2,
    const int* __restrict__ bucket, const int* __restrict__ counts, float* __restrict__ pooled)
{
    __shared__ short As[BM * BKS];
    __shared__ short Bs[BN * BKS];
    __shared__ int ridx[BM];
    __shared__ int saoff[C_NUM + 1];

    int tid = threadIdx.x;
    if (tid == 0) {
        int off = 0;
        for (int c2 = 0; c2 < C_NUM; ++c2) {
            saoff[c2] = off;
            off += ((counts[c2] + BM - 1) / BM) * BM;
        }
        saoff[C_NUM] = off;
    }
    __syncthreads();

    int wg = xcd_swizzle(blockIdx.x, gridDim.x);
    int rowStart = (wg >> 2) * BM;
    if (rowStart >= saoff[C_NUM]) return;
    int c = 0;
    while (c < C_NUM - 1 && rowStart >= saoff[c + 1]) ++c;
    int colStart = (wg & 3) * BN;

    int lane = tid & 63;
    int wid = tid >> 6;
    int wm = wid >> 1, wn = wid & 1;

    if (tid < BM) ridx[tid] = bucket[rowStart + tid];

    int l8 = lane >> 3;
    int sslot = (lane & 7) ^ l8;
    const short* abase = h1 + (size_t)(rowStart + l8) * D_H + sslot * 8;
    const short* bbase = Wt + ((size_t)c * D_H + colStart + l8) * D_H + sslot * 8;

    f32x4 acc[4][4];
#pragma unroll
    for (int i = 0; i < 4; ++i)
#pragma unroll
        for (int j = 0; j < 4; ++j)
            acc[i][j] = f32x4{0.f, 0.f, 0.f, 0.f};

    for (int k0 = 0; k0 < D_H; k0 += BKS) {
#pragma unroll
        for (int q = 0; q < 4; ++q) {
            int rb = (q * 4 + wid) * 8;
            gload_lds16(abase + (size_t)rb * D_H + k0, &As[rb * BKS]);
            gload_lds16(bbase + (size_t)rb * D_H + k0, &Bs[rb * BKS]);
        }
        __syncthreads();
#pragma unroll
        for (int kk = 0; kk < 2; ++kk) {
            short8v af[4], bfr[4];
#pragma unroll
            for (int i = 0; i < 4; ++i) {
                int row = wm * 64 + i * 16 + (lane & 15);
                int slot = (kk * 4 + (lane >> 4)) ^ (row & 7);
                af[i] = *(const short8v*)&As[row * BKS + slot * 8];
            }
#pragma unroll
            for (int j = 0; j < 4; ++j) {
                int nn = wn * 64 + j * 16 + (lane & 15);
                int slot = (kk * 4 + (lane >> 4)) ^ (nn & 7);
                bfr[j] = *(const short8v*)&Bs[nn * BKS + slot * 8];
            }
#pragma unroll
            for (int i = 0; i < 4; ++i)
#pragma unroll
                for (int j = 0; j < 4; ++j)
                    acc[i][j] = __builtin_amdgcn_mfma_f32_16x16x32_bf16(af[i], bfr[j], acc[i][j], 0, 0, 0);
        }
        __syncthreads();
    }

    const float* bias = b2 + c * D_H;
    float bj[4];
#pragma unroll
    for (int j = 0; j < 4; ++j) bj[j] = bias[colStart + wn * 64 + j * 16 + (lane & 15)];
    float csum[4] = {0.f, 0.f, 0.f, 0.f};
#pragma unroll
    for (int i = 0; i < 4; ++i) {
#pragma unroll
        for (int r = 0; r < 4; ++r) {
            int rowl = wm * 64 + i * 16 + (lane >> 4) * 4 + r;
            float m = (ridx[rowl] >= 0) ? 1.f : 0.f;
#pragma unroll
            for (int j = 0; j < 4; ++j)
                csum[j] += m * fmaxf(acc[i][j][r] + bj[j], 0.f);
        }
    }
#pragma unroll
    for (int j = 0; j < 4; ++j) {
        float s = csum[j];
        s += __shfl_xor(s, 16, 64);
        s += __shfl_xor(s, 32, 64);
        if ((lane >> 4) == 0)
            atomicAdd(&pooled[c * D_H + colStart + wn * 64 + j * 16 + lane], s);
    }
}

// ---- tail stage A: hfc = relu(hc @ Wfc + bfc) ----
__global__ __launch_bounds__(256) void k_tA(
    const float* __restrict__ pooled, const int* __restrict__ counts,
    const float* __restrict__ Wfc, const float* __restrict__ bfc,
    float* __restrict__ hfc)
{
    __shared__ float hcs[C_NUM][D_H];
    __shared__ float red[4][64][C_NUM];
    int tid = threadIdx.x;
    for (int idx = tid; idx < C_NUM * D_H; idx += 256) {
        int cc = idx >> 9;
        hcs[cc][idx & (D_H - 1)] = pooled[idx] / fmaxf((float)counts[cc], 1.f);
    }
    __syncthreads();
    int col = blockIdx.x * 64 + (tid & 63);
    int kq = tid >> 6, k0 = kq * 128;
    float acc[C_NUM] = {};
    for (int k = 0; k < 128; ++k) {
        float wv = Wfc[(size_t)(k0 + k) * D_H + col];
#pragma unroll
        for (int cc = 0; cc < C_NUM; ++cc) acc[cc] += hcs[cc][k0 + k] * wv;
    }
#pragma unroll
    for (int cc = 0; cc < C_NUM; ++cc) red[kq][tid & 63][cc] = acc[cc];
    __syncthreads();
    if (kq == 0) {
        float bv = bfc[col];
#pragma unroll
        for (int cc = 0; cc < C_NUM; ++cc) {
            float s = red[0][tid][cc] + red[1][tid][cc] + red[2][tid][cc] + red[3][tid][cc];
            hfc[cc * D_H + col] = fmaxf(s + bv, 0.f);
        }
    }
}

// ---- tail stage B: gated attention scores ----
__global__ __launch_bounds__(256) void k_tB(
    const float* __restrict__ hfc,
    const float* __restrict__ Wa, const float* __restrict__ ba,
    const float* __restrict__ Wb, const float* __restrict__ bb,
    const float* __restrict__ Wc,
    float* __restrict__ scores)
{
    __shared__ float hfs[C_NUM][D_H];
    __shared__ float red[4][64][C_NUM][2];
    int tid = threadIdx.x;
    for (int idx = tid; idx < C_NUM * D_H; idx += 256) {
        hfs[idx >> 9][idx & (D_H - 1)] = hfc[idx];
    }
    __syncthreads();
    int ad = blockIdx.x * 64 + (tid & 63);
    int kq = tid >> 6, k0 = kq * 128;
    float sa[C_NUM] = {}, sb[C_NUM] = {};
    for (int k = 0; k < 128; ++k) {
        float wav = Wa[(size_t)(k0 + k) * D_ATT + ad];
        float wbv = Wb[(size_t)(k0 + k) * D_ATT + ad];
#pragma unroll
        for (int cc = 0; cc < C_NUM; ++cc) {
            float h = hfs[cc][k0 + k];
            sa[cc] += h * wav;
            sb[cc] += h * wbv;
        }
    }
#pragma unroll
    for (int cc = 0; cc < C_NUM; ++cc) {
        red[kq][tid & 63][cc][0] = sa[cc];
        red[kq][tid & 63][cc][1] = sb[cc];
    }
    __syncthreads();
    if (kq == 0) {
        float bav = ba[ad], bbv = bb[ad], wcv = Wc[ad];
#pragma unroll
        for (int cc = 0; cc < C_NUM; ++cc) {
            float sat = red[0][tid][cc][0] + red[1][tid][cc][0] + red[2][tid][cc][0] + red[3][tid][cc][0];
            float sbt = red[0][tid][cc][1] + red[1][tid][cc][1] + red[2][tid][cc][1] + red[3][tid][cc][1];
            float v = tanhf(sat + bav) * (1.f / (1.f + expf(-(sbt + bbv)))) * wcv;
            v += __shfl_xor(v, 1, 64); v += __shfl_xor(v, 2, 64); v += __shfl_xor(v, 4, 64);
            v += __shfl_xor(v, 8, 64); v += __shfl_xor(v, 16, 64); v += __shfl_xor(v, 32, 64);
            if (tid == 0) atomicAdd(&scores[cc], v);
        }
    }
}

// ---- tail C+D+E fused: softmax + hp-chunk + rho partial; last block runs
// classifier/hazards (ticket atomic; coherent re-reads via atomicAdd(p,0)) ----
__global__ __launch_bounds__(256) void k_tCDE(
    const float* __restrict__ scores, const float* __restrict__ bc,
    const float* __restrict__ hfc, const float* __restrict__ Wrho,
    float* __restrict__ hr_raw, int* __restrict__ done,
    const float* __restrict__ brho,
    const float* __restrict__ Wcls, const float* __restrict__ bcls,
    float* __restrict__ out)
{
    __shared__ float hps[32];
    __shared__ int amLast;
    int tid = threadIdx.x;
    int k0 = blockIdx.x * 32;
    if (tid < 32) {
        float sc2[C_NUM];
        float mx = -1e30f;
#pragma unroll
        for (int cc = 0; cc < C_NUM; ++cc) { sc2[cc] = scores[cc] + bc[0]; mx = fmaxf(mx, sc2[cc]); }
        float sum = 0.f;
#pragma unroll
        for (int cc = 0; cc < C_NUM; ++cc) { sc2[cc] = expf(sc2[cc] - mx); sum += sc2[cc]; }
        float s = 0.f;
#pragma unroll
        for (int cc = 0; cc < C_NUM; ++cc) s += (sc2[cc] / sum) * hfc[cc * D_H + k0 + tid];
        hps[tid] = s;
    }
    __syncthreads();
    float acc = 0.f;
#pragma unroll 8
    for (int k = 0; k < 32; ++k)
        acc += hps[k] * Wrho[(size_t)(k0 + k) * D_ATT + tid];
    atomicAdd(&hr_raw[tid], acc);

    __threadfence();
    if (tid == 0) amLast = (atomicAdd(done, 1) == (int)gridDim.x - 1);
    __syncthreads();
    if (!amLast) return;

    // stage E (last block only): coherent read via atomic RMW with 0
    __shared__ float cpart[4][N_CLS];
    int lane = tid & 63, w = tid >> 6;
    float hraw = atomicAdd(&hr_raw[tid], 0.f);
    float h = fmaxf(hraw + brho[tid], 0.f);
    f32x4 wv = *(const f32x4*)&Wcls[tid * N_CLS];
    float v[N_CLS];
#pragma unroll
    for (int l = 0; l < N_CLS; ++l) {
        v[l] = h * wv[l];
        v[l] += __shfl_xor(v[l], 1, 64); v[l] += __shfl_xor(v[l], 2, 64);
        v[l] += __shfl_xor(v[l], 4, 64); v[l] += __shfl_xor(v[l], 8, 64);
        v[l] += __shfl_xor(v[l], 16, 64); v[l] += __shfl_xor(v[l], 32, 64);
    }
    if (lane == 0) {
#pragma unroll
        for (int l = 0; l < N_CLS; ++l) cpart[w][l] = v[l];
    }
    __syncthreads();
    if (tid == 0) {
        float lg[N_CLS];
#pragma unroll
        for (int l = 0; l < N_CLS; ++l)
            lg[l] = cpart[0][l] + cpart[1][l] + cpart[2][l] + cpart[3][l] + bcls[l];
        int best = 0;
#pragma unroll
        for (int l = 1; l < N_CLS; ++l) if (lg[l] > lg[best]) best = l;
        float Sv = 1.f;
#pragma unroll
        for (int l = 0; l < N_CLS; ++l) {
            float hz = 1.f / (1.f + expf(-lg[l]));
            out[l] = hz;
            Sv *= (1.f - hz);
            out[4 + l] = Sv;
        }
        out[8] = (float)best;
    }
}

extern "C" void kernel_launch(void* const* d_in, const int* in_sizes, int n_in,
                              void* d_out, int out_size, void* d_ws, size_t ws_size,
                              hipStream_t stream)
{
    const float* x    = (const float*)d_in[0];
    const int*   cid  = (const int*)d_in[1];
    const float* W1   = (const float*)d_in[2];
    const float* b1   = (const float*)d_in[3];
    const float* W2   = (const float*)d_in[4];
    const float* b2   = (const float*)d_in[5];
    const float* Wfc  = (const float*)d_in[6];
    const float* bfc  = (const float*)d_in[7];
    const float* Wa   = (const float*)d_in[8];
    const float* ba   = (const float*)d_in[9];
    const float* Wb   = (const float*)d_in[10];
    const float* bb   = (const float*)d_in[11];
    const float* Wc   = (const float*)d_in[12];
    const float* bc   = (const float*)d_in[13];
    const float* Wrho = (const float*)d_in[14];
    const float* brho = (const float*)d_in[15];
    const float* Wcls = (const float*)d_in[16];
    const float* bcls = (const float*)d_in[17];
    float* out = (float*)d_out;

    int n = in_sizes[0] / D_IN;                       // 20000
    int rowTiles = (n + BM - 1) / BM + C_NUM;         // worst-case tiles (167)
    int npadMax = rowTiles * BM;

    // workspace layout; leading region zeroed by one memset
    char* w = (char*)d_ws;
    int* counts   = (int*)w;                          // [16]
    int* cursor   = counts + 16;                      // [16]
    float* scores = (float*)(counts + 32);            // [16]
    int* done     = (int*)(scores + 16);              // [16]
    float* hr_raw = (float*)(done + 16);              // [256]
    float* pooled = hr_raw + 256;                     // [5120]
    size_t zero_bytes = (size_t)(16 + 16 + 16 + 16 + 256 + 5120) * 4;
    float* hfc  = pooled + 5120;                      // [5120]
    int* bucket = (int*)(hfc + 5120);                 // [npadMax]
    short* Wt1 = (short*)(bucket + npadMax);          // C*512*1024
    short* Wt2 = Wt1 + (size_t)C_NUM * D_H * D_IN;    // C*512*512
    short* h1  = Wt2 + (size_t)C_NUM * D_H * D_H;     // npadMax*512

    hipMemsetAsync(w, 0, zero_bytes, stream);

    int nb = (n + 255) / 256;
    k_hist<<<nb, 256, 0, stream>>>(cid, counts, n);
    k_scatter<<<nb, 256, 0, stream>>>(cid, cursor, counts, bucket, n);

    k_transpose2<<<C_NUM * 128 + C_NUM * 64, 256, 0, stream>>>(W1, Wt1, W2, Wt2);

    k_gemm1x<<<rowTiles * 4, 256, 0, stream>>>(x, Wt1, b1, bucket, counts, h1);
    k_gemm2_mfma<<<rowTiles * 4, 256, 0, stream>>>(h1, Wt2, b2, bucket, counts, pooled);

    k_tA<<<8, 256, 0, stream>>>(pooled, counts, Wfc, bfc, hfc);
    k_tB<<<4, 256, 0, stream>>>(hfc, Wa, ba, Wb, bb, Wc, scores);
    k_tCDE<<<16, 256, 0, stream>>>(scores, bc, hfc, Wrho, hr_raw, done,
                                   brho, Wcls, bcls, out);
}